// Round 6
// baseline (44.131 us; speedup 1.0000x reference)
//
#include <hip/hip_runtime.h>

// score[e] = dot(h[src[e]], h[dst[e]]), D=32.
// h converted once to bf16 in d_ws (6.4 MB, one 64-B line per row).
// Edge kernel: 4 lanes/edge, 16 B per lane -> 16 distinct lines per gather
// instruction; 2-step shfl reduce; coalesced store.
// All STREAMING accesses (indices, out, f32 h read) are non-temporal so the
// per-XCD L2 retains only the bf16 gather working set.
// Note: __builtin_nontemporal_* requires clang ext_vector_type, not
// HIP_vector_type (float4) -> use f32x4/u32x4 typedefs.

constexpr int D_FEAT = 32;

typedef float f32x4 __attribute__((ext_vector_type(4)));
typedef unsigned int u32x4 __attribute__((ext_vector_type(4)));
typedef unsigned short u16x4 __attribute__((ext_vector_type(4)));

static __device__ __forceinline__ float bf_lo(unsigned u) {
    return __uint_as_float(u << 16);
}
static __device__ __forceinline__ float bf_hi(unsigned u) {
    return __uint_as_float(u & 0xffff0000u);
}
static __device__ __forceinline__ unsigned short f2bf_rne(float f) {
    unsigned u = __float_as_uint(f);
    u = (u + 0x7fffu + ((u >> 16) & 1u)) >> 16;  // round-nearest-even
    return (unsigned short)u;
}

static __device__ __forceinline__ float dot8(u32x4 a, u32x4 b) {
    float acc;
    acc  = bf_lo(a.x) * bf_lo(b.x) + bf_hi(a.x) * bf_hi(b.x);
    acc += bf_lo(a.y) * bf_lo(b.y) + bf_hi(a.y) * bf_hi(b.y);
    acc += bf_lo(a.z) * bf_lo(b.z) + bf_hi(a.z) * bf_hi(b.z);
    acc += bf_lo(a.w) * bf_lo(b.w) + bf_hi(a.w) * bf_hi(b.w);
    return acc;
}

__global__ void __launch_bounds__(256) convert_h_bf16(
    const f32x4* __restrict__ h4, u16x4* __restrict__ hb4, int n4)
{
    int i = blockIdx.x * blockDim.x + threadIdx.x;
    const int stride = gridDim.x * blockDim.x;
    for (; i < n4; i += stride) {
        const f32x4 v = __builtin_nontemporal_load(&h4[i]);  // streamed once
        u16x4 o;
        o.x = f2bf_rne(v.x);
        o.y = f2bf_rne(v.y);
        o.z = f2bf_rne(v.z);
        o.w = f2bf_rne(v.w);
        hb4[i] = o;  // normal store: pre-warms L2 with the gather array
    }
}

__global__ void __launch_bounds__(256) edge_dot_bf16(
    const unsigned short* __restrict__ hb,
    const int* __restrict__ src,
    const int* __restrict__ dst,
    float* __restrict__ out,
    int n_edges)
{
    const int g = threadIdx.x & 3;  // lane-in-group: 4 lanes/edge, 16 B each
    const int group = (blockIdx.x * blockDim.x + threadIdx.x) >> 2;
    const int n_groups = (gridDim.x * blockDim.x) >> 2;

    for (int e = group; e < n_edges; e += n_groups) {
        const int s = __builtin_nontemporal_load(&src[e]);  // streamed once
        const int d = __builtin_nontemporal_load(&dst[e]);
        const u32x4 a = reinterpret_cast<const u32x4*>(hb + (size_t)s * D_FEAT)[g];
        const u32x4 b = reinterpret_cast<const u32x4*>(hb + (size_t)d * D_FEAT)[g];
        float acc = dot8(a, b);
        acc += __shfl_xor(acc, 1);
        acc += __shfl_xor(acc, 2);
        if (g == 0) __builtin_nontemporal_store(acc, &out[e]);  // streamed once
    }
}

// f32 fallback (if ws too small for bf16 copy of h)
__global__ void __launch_bounds__(256) edge_dot_f32(
    const float* __restrict__ h,
    const int* __restrict__ src,
    const int* __restrict__ dst,
    float* __restrict__ out,
    int n_edges)
{
    const int g = threadIdx.x & 7;
    const int group = (blockIdx.x * blockDim.x + threadIdx.x) >> 3;
    const int n_groups = (gridDim.x * blockDim.x) >> 3;
    for (int e = group; e < n_edges; e += n_groups) {
        const int s = src[e];
        const int d = dst[e];
        const f32x4 a = reinterpret_cast<const f32x4*>(h + (size_t)s * D_FEAT)[g];
        const f32x4 b = reinterpret_cast<const f32x4*>(h + (size_t)d * D_FEAT)[g];
        float acc = a.x * b.x + a.y * b.y + a.z * b.z + a.w * b.w;
        acc += __shfl_xor(acc, 1);
        acc += __shfl_xor(acc, 2);
        acc += __shfl_xor(acc, 4);
        if (g == 0) out[e] = acc;
    }
}

extern "C" void kernel_launch(void* const* d_in, const int* in_sizes, int n_in,
                              void* d_out, int out_size, void* d_ws, size_t ws_size,
                              hipStream_t stream) {
    const float* h   = (const float*)d_in[0];
    const int*   src = (const int*)d_in[1];
    const int*   dst = (const int*)d_in[2];
    float*       out = (float*)d_out;
    const int n_h     = in_sizes[0];           // N_NODES * D_FEAT
    const int n_edges = in_sizes[1];

    const size_t need = (size_t)n_h * sizeof(unsigned short);
    if (ws_size >= need) {
        unsigned short* hb = (unsigned short*)d_ws;
        const int n4 = n_h / 4;
        convert_h_bf16<<<2048, 256, 0, stream>>>(
            (const f32x4*)h, (u16x4*)hb, n4);
        edge_dot_bf16<<<2048, 256, 0, stream>>>(hb, src, dst, out, n_edges);
    } else {
        edge_dot_f32<<<2048, 256, 0, stream>>>(h, src, dst, out, n_edges);
    }
}